// Round 6
// baseline (267.487 us; speedup 1.0000x reference)
//
#include <hip/hip_runtime.h>
#include <math.h>

#define DIMX 384
#define SEQL 2048
#define NBATCH 2
#define DINNER 768
#define NSTATE 16
#define DTRANK 24
#define NTOK (NBATCH*SEQL)
#define NCHUNK 32
#define CHUNK (SEQL/NCHUNK)   // 64
#define NCH (2*NBATCH*DINNER) // 3072 channels (dir,b,d)
#define NGRP (NCH*NCHUNK)     // 98304 channel-chunk groups
#define KSPL 4                // xproj K-split
#define KS (DINNER/KSPL)      // 192

typedef __attribute__((ext_vector_type(8))) short bf16x8;
typedef __attribute__((ext_vector_type(8))) unsigned short u16x8;
typedef __attribute__((ext_vector_type(4))) float f32x4;

__device__ __forceinline__ float silu_f(float x) {
  return x / (1.f + __expf(-x));
}

__device__ __forceinline__ unsigned short f2bf(float f) {
  unsigned int u = __float_as_uint(f);
  unsigned int r = u + 0x7fffu + ((u >> 16) & 1u);   // round-to-nearest-even
  return (unsigned short)(r >> 16);
}

// ---------------- GEMM1 (bf16 MFMA): H[m][j] = sum_k X[m][k]*W[j][k] + bias[j] ----------------
__global__ __launch_bounds__(256) void k_lin(const float* __restrict__ X,
    const float* __restrict__ W, const float* __restrict__ bias,
    float* __restrict__ H) {
  __shared__ unsigned short LA[64][40];
  __shared__ unsigned short LB[64][40];
  const int m0 = blockIdx.x * 64, n0 = blockIdx.y * 64;
  const int tid = threadIdx.x, lane = tid & 63, w = tid >> 6;
  const int wm = (w >> 1) * 32, wn = (w & 1) * 32;
  const int fr = lane & 15, fg = lane >> 4;
  const int srow = tid >> 2, skg = (tid & 3) * 8;
  f32x4 acc[2][2] = {};
  for (int k0 = 0; k0 < DIMX; k0 += 32) {
    const float* ga = &X[(size_t)(m0 + srow) * DIMX + k0 + skg];
    const float* gb = &W[(size_t)(n0 + srow) * DIMX + k0 + skg];
    float4 a1 = *(const float4*)ga, a2 = *(const float4*)(ga + 4);
    float4 b1 = *(const float4*)gb, b2 = *(const float4*)(gb + 4);
    u16x8 va, vb;
    va[0]=f2bf(a1.x); va[1]=f2bf(a1.y); va[2]=f2bf(a1.z); va[3]=f2bf(a1.w);
    va[4]=f2bf(a2.x); va[5]=f2bf(a2.y); va[6]=f2bf(a2.z); va[7]=f2bf(a2.w);
    vb[0]=f2bf(b1.x); vb[1]=f2bf(b1.y); vb[2]=f2bf(b1.z); vb[3]=f2bf(b1.w);
    vb[4]=f2bf(b2.x); vb[5]=f2bf(b2.y); vb[6]=f2bf(b2.z); vb[7]=f2bf(b2.w);
    *(u16x8*)&LA[srow][skg] = va;
    *(u16x8*)&LB[srow][skg] = vb;
    __syncthreads();
    bf16x8 af[2], bfr[2];
    af[0]  = *(const bf16x8*)&LA[wm + fr][fg*8];
    af[1]  = *(const bf16x8*)&LA[wm + 16 + fr][fg*8];
    bfr[0] = *(const bf16x8*)&LB[wn + fr][fg*8];
    bfr[1] = *(const bf16x8*)&LB[wn + 16 + fr][fg*8];
#pragma unroll
    for (int i = 0; i < 2; ++i)
#pragma unroll
      for (int j = 0; j < 2; ++j)
        acc[i][j] = __builtin_amdgcn_mfma_f32_16x16x32_bf16(af[i], bfr[j], acc[i][j], 0, 0, 0);
    __syncthreads();
  }
#pragma unroll
  for (int i = 0; i < 2; ++i)
#pragma unroll
    for (int j = 0; j < 2; ++j)
#pragma unroll
      for (int r = 0; r < 4; ++r) {
        int m = m0 + wm + i*16 + fg*4 + r;
        int n = n0 + wn + j*16 + fr;
        H[(size_t)m * DIMX + n] = acc[i][j][r] + bias[n];
      }
}

// ---------------- LayerNorm + ReLU (in place on H) ----------------
__global__ __launch_bounds__(128) void k_ln(float* __restrict__ H,
    const float* __restrict__ g, const float* __restrict__ bt) {
  const int tok = blockIdx.x;
  float* row = H + (size_t)tok * DIMX;
  const int tid = threadIdx.x;
  float v[3]; float s = 0.f, ss = 0.f;
#pragma unroll
  for (int i = 0; i < 3; ++i) { v[i] = row[tid + i*128]; s += v[i]; ss += v[i]*v[i]; }
  for (int o = 32; o; o >>= 1) { s += __shfl_down(s, o); ss += __shfl_down(ss, o); }
  __shared__ float red[4];
  if ((tid & 63) == 0) { red[(tid>>6)*2] = s; red[(tid>>6)*2+1] = ss; }
  __syncthreads();
  float S = red[0] + red[2], SS = red[1] + red[3];
  float mu = S / DIMX;
  float var = SS / DIMX - mu * mu;
  float inv = rsqrtf(var + 1e-5f);
#pragma unroll
  for (int i = 0; i < 3; ++i) {
    int j = tid + i*128;
    float t = (v[i] - mu) * inv * g[j] + bt[j];
    row[j] = t > 0.f ? t : 0.f;
  }
}

// ---------------- GEMM2 (bf16 MFMA): XZ[b][c][l] = sum_k H[b][l][k]*W2[c][k] ----------------
__global__ __launch_bounds__(256) void k_inproj(const float* __restrict__ H,
    const float* __restrict__ W2, float* __restrict__ XZ) {
  __shared__ unsigned short LA[64][40];   // [c][k]
  __shared__ unsigned short LB[64][40];   // [tok][k]
  const int n0 = blockIdx.x * 64;         // token tile
  const int m0 = blockIdx.y * 64;         // channel tile
  const int tid = threadIdx.x, lane = tid & 63, w = tid >> 6;
  const int wm = (w >> 1) * 32, wn = (w & 1) * 32;
  const int fr = lane & 15, fg = lane >> 4;
  const int srow = tid >> 2, skg = (tid & 3) * 8;
  f32x4 acc[2][2] = {};
  for (int k0 = 0; k0 < DIMX; k0 += 32) {
    const float* ga = &W2[(size_t)(m0 + srow) * DIMX + k0 + skg];
    const float* gb = &H[(size_t)(n0 + srow) * DIMX + k0 + skg];
    float4 a1 = *(const float4*)ga, a2 = *(const float4*)(ga + 4);
    float4 b1 = *(const float4*)gb, b2 = *(const float4*)(gb + 4);
    u16x8 va, vb;
    va[0]=f2bf(a1.x); va[1]=f2bf(a1.y); va[2]=f2bf(a1.z); va[3]=f2bf(a1.w);
    va[4]=f2bf(a2.x); va[5]=f2bf(a2.y); va[6]=f2bf(a2.z); va[7]=f2bf(a2.w);
    vb[0]=f2bf(b1.x); vb[1]=f2bf(b1.y); vb[2]=f2bf(b1.z); vb[3]=f2bf(b1.w);
    vb[4]=f2bf(b2.x); vb[5]=f2bf(b2.y); vb[6]=f2bf(b2.z); vb[7]=f2bf(b2.w);
    *(u16x8*)&LA[srow][skg] = va;
    *(u16x8*)&LB[srow][skg] = vb;
    __syncthreads();
    bf16x8 af[2], bfr[2];
    af[0]  = *(const bf16x8*)&LA[wm + fr][fg*8];
    af[1]  = *(const bf16x8*)&LA[wm + 16 + fr][fg*8];
    bfr[0] = *(const bf16x8*)&LB[wn + fr][fg*8];
    bfr[1] = *(const bf16x8*)&LB[wn + 16 + fr][fg*8];
#pragma unroll
    for (int i = 0; i < 2; ++i)
#pragma unroll
      for (int j = 0; j < 2; ++j)
        acc[i][j] = __builtin_amdgcn_mfma_f32_16x16x32_bf16(af[i], bfr[j], acc[i][j], 0, 0, 0);
    __syncthreads();
  }
  const int b = n0 >> 11;
  const int lbase = n0 & (SEQL - 1);
#pragma unroll
  for (int i = 0; i < 2; ++i)
#pragma unroll
    for (int j = 0; j < 2; ++j)
#pragma unroll
      for (int r = 0; r < 4; ++r) {
        int c = m0 + wm + i*16 + fg*4 + r;
        int l = lbase + wn + j*16 + fr;
        XZ[((size_t)(b*(2*DINNER) + c)) * SEQL + l] = acc[i][j][r];
      }
}

// ---------------- causal depthwise conv + silu (both directions) ----------------
__global__ __launch_bounds__(256) void k_conv(const float* __restrict__ XZ,
    const float* __restrict__ cw, const float* __restrict__ cb,
    float* __restrict__ XC) {
  const int idx = blockIdx.x * 256 + threadIdx.x;  // over 2*NB*DI*L
  const int t = idx & (SEQL - 1);
  const int c = idx >> 11;
  const int d = c % DINNER;
  const int bb = c / DINNER;
  const int b = bb & (NBATCH - 1);
  const int dir = bb >> 1;
  const float* row = XZ + (size_t)(b*(2*DINNER) + d) * SEQL;
  float s = cb[d];
  const float w0 = cw[d*4+0], w1 = cw[d*4+1], w2 = cw[d*4+2], w3 = cw[d*4+3];
  if (dir == 0) {
    if (t >= 3) s += w0 * row[t-3];
    if (t >= 2) s += w1 * row[t-2];
    if (t >= 1) s += w2 * row[t-1];
    s += w3 * row[t];
  } else {
    int base = SEQL - 1 - t;
    if (base + 3 < SEQL) s += w0 * row[base+3];
    if (base + 2 < SEQL) s += w1 * row[base+2];
    if (base + 1 < SEQL) s += w2 * row[base+1];
    s += w3 * row[base];
  }
  XC[idx] = silu_f(s);
}

// ---------------- x_proj split-K partial: PART[ks][db][n][t] ----------------
__global__ __launch_bounds__(256) void k_xproj_part(const float* __restrict__ XC,
    const float* __restrict__ XPW, float* __restrict__ PART) {
  __shared__ float As[64][33];
  __shared__ float Ws[64][57];
  const int l0 = blockIdx.x * 32;
  const int ks = blockIdx.y;
  const int db = blockIdx.z;          // dir*NBATCH + b
  const int tid = threadIdx.x;
  const int ll = tid & 31, g = tid >> 5;  // 8 groups x 7 outputs
  const float* xc = XC + (size_t)db * DINNER * SEQL;
  float acc[7] = {};
  const int kbase = ks * KS;
  for (int k0 = kbase; k0 < kbase + KS; k0 += 64) {
#pragma unroll
    for (int i = 0; i < 8; ++i) {
      int e = tid + i*256;
      int kk = e >> 5, cc = e & 31;
      As[kk][cc] = xc[(size_t)(k0 + kk) * SEQL + l0 + cc];
    }
#pragma unroll
    for (int i = 0; i < 14; ++i) {
      int e = tid + i*256;
      if (e < 64*56) { int kk = e / 56, n = e % 56; Ws[kk][n] = XPW[(size_t)n * DINNER + k0 + kk]; }
    }
    __syncthreads();
#pragma unroll 8
    for (int kk = 0; kk < 64; ++kk) {
      float a = As[kk][ll];
#pragma unroll
      for (int i = 0; i < 7; ++i) acc[i] = fmaf(a, Ws[kk][g*7+i], acc[i]);
    }
    __syncthreads();
  }
#pragma unroll
  for (int i = 0; i < 7; ++i) {
    int n = g*7 + i;
    PART[((size_t)(ks*4 + db) * 56 + n) * SEQL + l0 + ll] = acc[i];
  }
}

// ---------------- x_proj reduce: sum partials -> DTR / BC layouts ----------------
__global__ __launch_bounds__(256) void k_xred(const float* __restrict__ PART,
    float* __restrict__ DTR, float* __restrict__ BC) {
  const int idx = blockIdx.x * 256 + threadIdx.x;  // over 4*56*SEQL
  const int db = idx / (56 * SEQL);
  const int r  = idx % (56 * SEQL);
  const int n  = r / SEQL;
  const int t  = r % SEQL;
  float s = 0.f;
#pragma unroll
  for (int ks = 0; ks < KSPL; ++ks)
    s += PART[((size_t)(ks*4 + db) * 56 + n) * SEQL + t];
  if (n < DTRANK)
    DTR[((size_t)db * DTRANK + n) * SEQL + t] = s;
  else
    BC[((size_t)db * SEQL + t) * 32 + (n - DTRANK)] = s;
}

// ---------------- dt_proj + softplus -> delta ----------------
__global__ __launch_bounds__(256) void k_dtproj(const float* __restrict__ DTR,
    const float* __restrict__ WDT, const float* __restrict__ BDT,
    float* __restrict__ DELTA) {
  __shared__ float S[DTRANK][256];
  const int t0 = blockIdx.x * 256;
  const int d0 = blockIdx.y * 8;
  const int db = blockIdx.z;  // dir*NBATCH + b
  const int tid = threadIdx.x;
  const float* src = DTR + (size_t)(db * DTRANK) * SEQL;
#pragma unroll
  for (int r = 0; r < DTRANK; ++r) S[r][tid] = src[(size_t)r * SEQL + t0 + tid];
  __syncthreads();
#pragma unroll
  for (int i = 0; i < 8; ++i) {
    int d = d0 + i;
    float s = BDT[d];
#pragma unroll
    for (int r = 0; r < DTRANK; ++r) s = fmaf(WDT[d*DTRANK + r], S[r][tid], s);
    float sp = fmaxf(s, 0.f) + log1pf(__expf(-fabsf(s)));
    DELTA[(size_t)(db * DINNER + d) * SEQL + t0 + tid] = sp;
  }
}

// ---------------- chunked scan pass 1: shuffle-free (quad-uniform f4 loads) ----------------
__global__ __launch_bounds__(256) void k_scan1(const float* __restrict__ DELTA,
    const float* __restrict__ XC, const float* __restrict__ BC,
    const float* __restrict__ Alog, const float* __restrict__ Ablog,
    float* __restrict__ DS, float* __restrict__ HL) {
  const int tid = threadIdx.x;
  const int lk = tid & 3;                         // lane in quad = state quad
  const int gid = blockIdx.x * 64 + (tid >> 2);   // channel-chunk group
  const int c = gid & (NCHUNK - 1);
  const int ch = gid >> 5;                        // /NCHUNK (=32)
  const int d = ch % DINNER;
  const int rest = ch / DINNER;
  const int b = rest & (NBATCH - 1);
  const int dir = rest >> 1;
  const float* Ap = (dir ? Ablog : Alog) + (size_t)d * NSTATE + 4*lk;
  float Av[4];
#pragma unroll
  for (int j = 0; j < 4; ++j) Av[j] = -__expf(Ap[j]);
  const float* dlt_p = DELTA + (size_t)((dir*NBATCH + b) * DINNER + d) * SEQL;
  const float* xc_p  = XC   + (size_t)((dir*NBATCH + b) * DINNER + d) * SEQL;
  const float* bc_p  = BC   + (size_t)(dir*NBATCH + b) * SEQL * 32;
  float h[4] = {0.f, 0.f, 0.f, 0.f};
  float dsum = 0.f;
  const int t0 = c * CHUNK;
#pragma unroll 2
  for (int tb = t0; tb < t0 + CHUNK; tb += 4) {
    float4 d4 = *(const float4*)&dlt_p[tb];   // quad-uniform: HW broadcast
    float4 x4 = *(const float4*)&xc_p[tb];
    float dl[4] = {d4.x, d4.y, d4.z, d4.w};
    float xv[4] = {x4.x, x4.y, x4.z, x4.w};
    dsum += d4.x + d4.y + d4.z + d4.w;
#pragma unroll
    for (int k = 0; k < 4; ++k) {
      float u = dl[k] * xv[k];
      float4 b4 = *(const float4*)&bc_p[(tb + k)*32 + 4*lk];
      float bb[4] = {b4.x, b4.y, b4.z, b4.w};
#pragma unroll
      for (int j = 0; j < 4; ++j) {
        float dA = __expf(dl[k] * Av[j]);
        h[j] = fmaf(dA, h[j], u * bb[j]);
      }
    }
  }
  if (lk == 0) DS[gid] = dsum;
  float4 hv = {h[0], h[1], h[2], h[3]};
  *(float4*)&HL[(size_t)gid * 16 + 4*lk] = hv;
}

// ---------------- fixup: h_start per chunk via P = exp(A * sum_delta) ----------------
__global__ __launch_bounds__(256) void k_scanfix(const float* __restrict__ DS,
    const float* __restrict__ HL, const float* __restrict__ Alog,
    const float* __restrict__ Ablog, float* __restrict__ HS) {
  const int idx = blockIdx.x * 256 + threadIdx.x;  // 0 .. NCH*16-1
  const int ch = idx >> 4;
  const int n = idx & 15;
  const int d = ch % DINNER;
  const int rest = ch / DINNER;
  const int dir = rest >> 1;
  const float Aval = -__expf((dir ? Ablog : Alog)[(size_t)d * NSTATE + n]);
  float h = 0.f;
#pragma unroll
  for (int c = 0; c < NCHUNK; ++c) {
    size_t off = ((size_t)ch * NCHUNK + c) * 16 + n;
    HS[off] = h;
    float p = __expf(DS[(size_t)ch * NCHUNK + c] * Aval);
    h = fmaf(p, h, HL[off]);
  }
}

// ---------------- chunked scan pass 2: shuffle-light, quad transpose-reduce for y ----------------
__global__ __launch_bounds__(256) void k_scan2(const float* __restrict__ DELTA,
    const float* __restrict__ XC, const float* __restrict__ BC,
    const float* __restrict__ XZ, const float* __restrict__ Alog,
    const float* __restrict__ Ablog, const float* __restrict__ Dp,
    const float* __restrict__ HS, float* __restrict__ Y) {
  const int tid = threadIdx.x;
  const int lk = tid & 3;
  const int gid = blockIdx.x * 64 + (tid >> 2);
  const int c = gid & (NCHUNK - 1);
  const int ch = gid >> 5;
  const int d = ch % DINNER;
  const int rest = ch / DINNER;
  const int b = rest & (NBATCH - 1);
  const int dir = rest >> 1;
  const float* Ap = (dir ? Ablog : Alog) + (size_t)d * NSTATE + 4*lk;
  float Av[4];
#pragma unroll
  for (int j = 0; j < 4; ++j) Av[j] = -__expf(Ap[j]);
  const float Dd = Dp[d];
  const float* dlt_p = DELTA + (size_t)((dir*NBATCH + b) * DINNER + d) * SEQL;
  const float* xc_p  = XC   + (size_t)((dir*NBATCH + b) * DINNER + d) * SEQL;
  const float* bc_p  = BC   + (size_t)(dir*NBATCH + b) * SEQL * 32;
  const float* z_p   = XZ   + (size_t)(b*(2*DINNER) + DINNER + d) * SEQL;
  float* y_p = Y + (size_t)((dir*NBATCH + b) * DINNER + d) * SEQL;
  float4 h0 = *(const float4*)&HS[(size_t)gid * 16 + 4*lk];
  float h[4] = {h0.x, h0.y, h0.z, h0.w};
  const int t0 = c * CHUNK;
#pragma unroll 2
  for (int tb = t0; tb < t0 + CHUNK; tb += 4) {
    float4 d4 = *(const float4*)&dlt_p[tb];   // quad-uniform
    float4 x4 = *(const float4*)&xc_p[tb];
    float4 z4 = dir ? *(const float4*)&z_p[SEQL - 4 - tb]
                    : *(const float4*)&z_p[tb];
    float dl[4] = {d4.x, d4.y, d4.z, d4.w};
    float xv[4] = {x4.x, x4.y, x4.z, x4.w};
    float zl[4] = {z4.x, z4.y, z4.z, z4.w};
    float pp[4];
#pragma unroll
    for (int k = 0; k < 4; ++k) {
      float u = dl[k] * xv[k];
      float4 b4 = *(const float4*)&bc_p[(tb + k)*32 + 4*lk];
      float4 c4 = *(const float4*)&bc_p[(tb + k)*32 + 16 + 4*lk];
      float bb[4] = {b4.x, b4.y, b4.z, b4.w};
      float cc[4] = {c4.x, c4.y, c4.z, c4.w};
      float py = 0.f;
#pragma unroll
      for (int j = 0; j < 4; ++j) {
        float dA = __expf(dl[k] * Av[j]);
        h[j] = fmaf(dA, h[j], u * bb[j]);
        py = fmaf(h[j], cc[j], py);
      }
      pp[k] = py;
    }
    // 4x4 quad transpose-reduce: lane lk ends with y[tb+lk] = sum over lanes of pp[lk]
    const int i0 = lk & 1;
    float u0 = __shfl_xor(pp[i0 ^ 1], 1, 4);
    float u1 = __shfl_xor(pp[(i0 ^ 1) + 2], 1, 4);
    float s0 = pp[i0] + u0;          // index i0
    float s1 = pp[i0 + 2] + u1;      // index i0+2
    float send = (lk & 2) ? s0 : s1;
    float v = __shfl_xor(send, 2, 4);
    float keep = (lk & 2) ? s1 : s0;
    float ysum = keep + v;
    const int tcur = tb + lk;
    float gz = silu_f(dir ? zl[3 - lk] : zl[lk]);
    float yv = fmaf(xv[lk], Dd, ysum) * gz;
    const int to = dir ? (SEQL - 1 - tcur) : tcur;
    y_p[to] = yv;
  }
}

// ---------------- out_proj (bf16 MFMA) + residual ----------------
// OUT[tok][o] = sum_k (y0[k][tok]+y1[k][tok]) * WO[o][k] + X[tok][o]
__global__ __launch_bounds__(256) void k_outproj(const float* __restrict__ Y,
    const float* __restrict__ WO, const float* __restrict__ X,
    float* __restrict__ OUT) {
  __shared__ unsigned short LA[64][40];   // [tok][k] (transposed stage)
  __shared__ unsigned short LB[64][40];   // [o][k]
  const int m0 = blockIdx.x * 64;         // token tile
  const int n0 = blockIdx.y * 64;         // output-dim tile
  const int tid = threadIdx.x, lane = tid & 63, w = tid >> 6;
  const int wm = (w >> 1) * 32, wn = (w & 1) * 32;
  const int fr = lane & 15, fg = lane >> 4;
  const int b = m0 >> 11, lb = m0 & (SEQL - 1);
  const float* y0 = Y + (size_t)b * DINNER * SEQL;
  const float* y1 = Y + (size_t)(NBATCH + b) * DINNER * SEQL;
  const int kk = tid >> 3, tg = (tid & 7) * 8;   // A staging: 32 k x 8 tok-groups
  const int srow = tid >> 2, skg = (tid & 3) * 8; // B staging
  f32x4 acc[2][2] = {};
  for (int k0 = 0; k0 < DINNER; k0 += 32) {
    const float* p0 = y0 + (size_t)(k0 + kk) * SEQL + lb + tg;
    const float* p1 = y1 + (size_t)(k0 + kk) * SEQL + lb + tg;
    float4 u0 = *(const float4*)p0, u1 = *(const float4*)(p0 + 4);
    float4 v0 = *(const float4*)p1, v1 = *(const float4*)(p1 + 4);
    float s[8] = {u0.x+v0.x, u0.y+v0.y, u0.z+v0.z, u0.w+v0.w,
                  u1.x+v1.x, u1.y+v1.y, u1.z+v1.z, u1.w+v1.w};
#pragma unroll
    for (int i = 0; i < 8; ++i) LA[tg + i][kk] = f2bf(s[i]);
    const float* gb = &WO[(size_t)(n0 + srow) * DINNER + k0 + skg];
    float4 b1 = *(const float4*)gb, b2 = *(const float4*)(gb + 4);
    u16x8 vb;
    vb[0]=f2bf(b1.x); vb[1]=f2bf(b1.y); vb[2]=f2bf(b1.z); vb[3]=f2bf(b1.w);
    vb[4]=f2bf(b2.x); vb[5]=f2bf(b2.y); vb[6]=f2bf(b2.z); vb[7]=f2bf(b2.w);
    *(u16x8*)&LB[srow][skg] = vb;
    __syncthreads();
    bf16x8 af[2], bfr[2];
    af[0]  = *(const bf16x8*)&LA[wm + fr][fg*8];
    af[1]  = *(const bf16x8*)&LA[wm + 16 + fr][fg*8];
    bfr[0] = *(const bf16x8*)&LB[wn + fr][fg*8];
    bfr[1] = *(const bf16x8*)&LB[wn + 16 + fr][fg*8];
#pragma unroll
    for (int i = 0; i < 2; ++i)
#pragma unroll
      for (int j = 0; j < 2; ++j)
        acc[i][j] = __builtin_amdgcn_mfma_f32_16x16x32_bf16(af[i], bfr[j], acc[i][j], 0, 0, 0);
    __syncthreads();
  }
#pragma unroll
  for (int i = 0; i < 2; ++i)
#pragma unroll
    for (int j = 0; j < 2; ++j)
#pragma unroll
      for (int r = 0; r < 4; ++r) {
        int tok = m0 + wm + i*16 + fg*4 + r;
        int o = n0 + wn + j*16 + fr;
        size_t off = (size_t)tok * DIMX + o;
        OUT[off] = acc[i][j][r] + X[off];
      }
}

extern "C" void kernel_launch(void* const* d_in, const int* in_sizes, int n_in,
                              void* d_out, int out_size, void* d_ws, size_t ws_size,
                              hipStream_t stream) {
  (void)in_sizes; (void)n_in; (void)out_size; (void)ws_size;
  const float* x         = (const float*)d_in[0];
  const float* lin_w     = (const float*)d_in[1];
  const float* lin_b     = (const float*)d_in[2];
  const float* ln_g      = (const float*)d_in[3];
  const float* ln_b      = (const float*)d_in[4];
  const float* in_proj_w = (const float*)d_in[5];
  const float* conv_w    = (const float*)d_in[6];
  const float* conv_b    = (const float*)d_in[7];
  const float* x_proj_w  = (const float*)d_in[8];
  const float* dt_proj_w = (const float*)d_in[9];
  const float* dt_proj_b = (const float*)d_in[10];
  const float* A_log     = (const float*)d_in[11];
  const float* A_b_log   = (const float*)d_in[12];
  const float* Dp        = (const float*)d_in[13];
  const float* out_proj_w= (const float*)d_in[14];
  float* out = (float*)d_out;

  float* ws = (float*)d_ws;
  float* h    = ws;  ws += (size_t)NTOK * DIMX;               // dead after k_inproj -> reused as HS
  float* xz   = ws;  ws += (size_t)NBATCH * 2*DINNER * SEQL;
  float* xc   = ws;  ws += (size_t)2 * NBATCH * DINNER * SEQL;
  float* dlt  = ws;  ws += (size_t)2 * NBATCH * DINNER * SEQL;
  float* dtr  = ws;  ws += (size_t)2 * NBATCH * DTRANK * SEQL;
  float* bc   = ws;  ws += (size_t)2 * NBATCH * SEQL * 32;
  float* y01  = ws;  ws += (size_t)2 * NBATCH * DINNER * SEQL;
  float* HLb  = ws;  ws += (size_t)NGRP * 16;
  float* DSb  = ws;  ws += (size_t)NGRP;
  float* HSb  = h;    // overlay: NGRP*16 == NTOK*DIMX, h dead after k_inproj
  float* PART = y01;  // overlay: KSPL*4*56*SEQL (1.84M) <= y01 (12.6M), y01 written later by k_scan2

  k_lin<<<dim3(NTOK/64, DIMX/64), 256, 0, stream>>>(x, lin_w, lin_b, h);
  k_ln<<<NTOK, 128, 0, stream>>>(h, ln_g, ln_b);
  k_inproj<<<dim3(NTOK/64, 2*DINNER/64), 256, 0, stream>>>(h, in_proj_w, xz);
  k_conv<<<(2*NBATCH*DINNER*SEQL)/256, 256, 0, stream>>>(xz, conv_w, conv_b, xc);
  k_xproj_part<<<dim3(SEQL/32, KSPL, 2*NBATCH), 256, 0, stream>>>(xc, x_proj_w, PART);
  k_xred<<<(2*NBATCH*56*SEQL)/256, 256, 0, stream>>>(PART, dtr, bc);
  k_dtproj<<<dim3(SEQL/256, DINNER/8, 2*NBATCH), 256, 0, stream>>>(dtr, dt_proj_w, dt_proj_b, dlt);
  k_scan1<<<NGRP*4/256, 256, 0, stream>>>(dlt, xc, bc, A_log, A_b_log, DSb, HLb);
  k_scanfix<<<NCH*16/256, 256, 0, stream>>>(DSb, HLb, A_log, A_b_log, HSb);
  k_scan2<<<NGRP*4/256, 256, 0, stream>>>(dlt, xc, bc, xz, A_log, A_b_log, Dp, HSb, y01);
  k_outproj<<<dim3(NTOK/64, DIMX/64), 256, 0, stream>>>(y01, out_proj_w, x, out);
}

// Round 7
// 249.323 us; speedup vs baseline: 1.0729x; 1.0729x over previous
//
#include <hip/hip_runtime.h>
#include <math.h>

#define DIMX 384
#define SEQL 2048
#define NBATCH 2
#define DINNER 768
#define NSTATE 16
#define DTRANK 24
#define NTOK (NBATCH*SEQL)
#define NCHUNK 32
#define CHUNK (SEQL/NCHUNK)   // 64
#define NCH (2*NBATCH*DINNER) // 3072 channels (dir,b,d)
#define NGRP (NCH*NCHUNK)     // 98304 channel-chunk groups
#define KSPL 4                // xproj K-split
#define KS (DINNER/KSPL)      // 192

typedef __attribute__((ext_vector_type(8))) short bf16x8;
typedef __attribute__((ext_vector_type(8))) unsigned short u16x8;
typedef __attribute__((ext_vector_type(4))) float f32x4;

__device__ __forceinline__ float silu_f(float x) {
  return x / (1.f + __expf(-x));
}

__device__ __forceinline__ unsigned short f2bf(float f) {
  unsigned int u = __float_as_uint(f);
  unsigned int r = u + 0x7fffu + ((u >> 16) & 1u);   // round-to-nearest-even
  return (unsigned short)(r >> 16);
}

__device__ __forceinline__ float bf2f(unsigned short u) {
  return __uint_as_float(((unsigned int)u) << 16);
}

// ---------------- GEMM1 (bf16 MFMA): H[m][j] = sum_k X[m][k]*W[j][k] + bias[j] ----------------
__global__ __launch_bounds__(256) void k_lin(const float* __restrict__ X,
    const float* __restrict__ W, const float* __restrict__ bias,
    float* __restrict__ H) {
  __shared__ unsigned short LA[64][40];
  __shared__ unsigned short LB[64][40];
  const int m0 = blockIdx.x * 64, n0 = blockIdx.y * 64;
  const int tid = threadIdx.x, lane = tid & 63, w = tid >> 6;
  const int wm = (w >> 1) * 32, wn = (w & 1) * 32;
  const int fr = lane & 15, fg = lane >> 4;
  const int srow = tid >> 2, skg = (tid & 3) * 8;
  f32x4 acc[2][2] = {};
  for (int k0 = 0; k0 < DIMX; k0 += 32) {
    const float* ga = &X[(size_t)(m0 + srow) * DIMX + k0 + skg];
    const float* gb = &W[(size_t)(n0 + srow) * DIMX + k0 + skg];
    float4 a1 = *(const float4*)ga, a2 = *(const float4*)(ga + 4);
    float4 b1 = *(const float4*)gb, b2 = *(const float4*)(gb + 4);
    u16x8 va, vb;
    va[0]=f2bf(a1.x); va[1]=f2bf(a1.y); va[2]=f2bf(a1.z); va[3]=f2bf(a1.w);
    va[4]=f2bf(a2.x); va[5]=f2bf(a2.y); va[6]=f2bf(a2.z); va[7]=f2bf(a2.w);
    vb[0]=f2bf(b1.x); vb[1]=f2bf(b1.y); vb[2]=f2bf(b1.z); vb[3]=f2bf(b1.w);
    vb[4]=f2bf(b2.x); vb[5]=f2bf(b2.y); vb[6]=f2bf(b2.z); vb[7]=f2bf(b2.w);
    *(u16x8*)&LA[srow][skg] = va;
    *(u16x8*)&LB[srow][skg] = vb;
    __syncthreads();
    bf16x8 af[2], bfr[2];
    af[0]  = *(const bf16x8*)&LA[wm + fr][fg*8];
    af[1]  = *(const bf16x8*)&LA[wm + 16 + fr][fg*8];
    bfr[0] = *(const bf16x8*)&LB[wn + fr][fg*8];
    bfr[1] = *(const bf16x8*)&LB[wn + 16 + fr][fg*8];
#pragma unroll
    for (int i = 0; i < 2; ++i)
#pragma unroll
      for (int j = 0; j < 2; ++j)
        acc[i][j] = __builtin_amdgcn_mfma_f32_16x16x32_bf16(af[i], bfr[j], acc[i][j], 0, 0, 0);
    __syncthreads();
  }
#pragma unroll
  for (int i = 0; i < 2; ++i)
#pragma unroll
    for (int j = 0; j < 2; ++j)
#pragma unroll
      for (int r = 0; r < 4; ++r) {
        int m = m0 + wm + i*16 + fg*4 + r;
        int n = n0 + wn + j*16 + fr;
        H[(size_t)m * DIMX + n] = acc[i][j][r] + bias[n];
      }
}

// ---------------- LayerNorm + ReLU (in place on H) ----------------
__global__ __launch_bounds__(128) void k_ln(float* __restrict__ H,
    const float* __restrict__ g, const float* __restrict__ bt) {
  const int tok = blockIdx.x;
  float* row = H + (size_t)tok * DIMX;
  const int tid = threadIdx.x;
  float v[3]; float s = 0.f, ss = 0.f;
#pragma unroll
  for (int i = 0; i < 3; ++i) { v[i] = row[tid + i*128]; s += v[i]; ss += v[i]*v[i]; }
  for (int o = 32; o; o >>= 1) { s += __shfl_down(s, o); ss += __shfl_down(ss, o); }
  __shared__ float red[4];
  if ((tid & 63) == 0) { red[(tid>>6)*2] = s; red[(tid>>6)*2+1] = ss; }
  __syncthreads();
  float S = red[0] + red[2], SS = red[1] + red[3];
  float mu = S / DIMX;
  float var = SS / DIMX - mu * mu;
  float inv = rsqrtf(var + 1e-5f);
#pragma unroll
  for (int i = 0; i < 3; ++i) {
    int j = tid + i*128;
    float t = (v[i] - mu) * inv * g[j] + bt[j];
    row[j] = t > 0.f ? t : 0.f;
  }
}

// ---------------- GEMM2 (bf16 MFMA): XZ[b][c][l] = sum_k H[b][l][k]*W2[c][k] ----------------
__global__ __launch_bounds__(256) void k_inproj(const float* __restrict__ H,
    const float* __restrict__ W2, float* __restrict__ XZ) {
  __shared__ unsigned short LA[64][40];   // [c][k]
  __shared__ unsigned short LB[64][40];   // [tok][k]
  const int n0 = blockIdx.x * 64;         // token tile
  const int m0 = blockIdx.y * 64;         // channel tile
  const int tid = threadIdx.x, lane = tid & 63, w = tid >> 6;
  const int wm = (w >> 1) * 32, wn = (w & 1) * 32;
  const int fr = lane & 15, fg = lane >> 4;
  const int srow = tid >> 2, skg = (tid & 3) * 8;
  f32x4 acc[2][2] = {};
  for (int k0 = 0; k0 < DIMX; k0 += 32) {
    const float* ga = &W2[(size_t)(m0 + srow) * DIMX + k0 + skg];
    const float* gb = &H[(size_t)(n0 + srow) * DIMX + k0 + skg];
    float4 a1 = *(const float4*)ga, a2 = *(const float4*)(ga + 4);
    float4 b1 = *(const float4*)gb, b2 = *(const float4*)(gb + 4);
    u16x8 va, vb;
    va[0]=f2bf(a1.x); va[1]=f2bf(a1.y); va[2]=f2bf(a1.z); va[3]=f2bf(a1.w);
    va[4]=f2bf(a2.x); va[5]=f2bf(a2.y); va[6]=f2bf(a2.z); va[7]=f2bf(a2.w);
    vb[0]=f2bf(b1.x); vb[1]=f2bf(b1.y); vb[2]=f2bf(b1.z); vb[3]=f2bf(b1.w);
    vb[4]=f2bf(b2.x); vb[5]=f2bf(b2.y); vb[6]=f2bf(b2.z); vb[7]=f2bf(b2.w);
    *(u16x8*)&LA[srow][skg] = va;
    *(u16x8*)&LB[srow][skg] = vb;
    __syncthreads();
    bf16x8 af[2], bfr[2];
    af[0]  = *(const bf16x8*)&LA[wm + fr][fg*8];
    af[1]  = *(const bf16x8*)&LA[wm + 16 + fr][fg*8];
    bfr[0] = *(const bf16x8*)&LB[wn + fr][fg*8];
    bfr[1] = *(const bf16x8*)&LB[wn + 16 + fr][fg*8];
#pragma unroll
    for (int i = 0; i < 2; ++i)
#pragma unroll
      for (int j = 0; j < 2; ++j)
        acc[i][j] = __builtin_amdgcn_mfma_f32_16x16x32_bf16(af[i], bfr[j], acc[i][j], 0, 0, 0);
    __syncthreads();
  }
  const int b = n0 >> 11;
  const int lbase = n0 & (SEQL - 1);
#pragma unroll
  for (int i = 0; i < 2; ++i)
#pragma unroll
    for (int j = 0; j < 2; ++j)
#pragma unroll
      for (int r = 0; r < 4; ++r) {
        int c = m0 + wm + i*16 + fg*4 + r;
        int l = lbase + wn + j*16 + fr;
        XZ[((size_t)(b*(2*DINNER) + c)) * SEQL + l] = acc[i][j][r];
      }
}

// ---------------- causal depthwise conv + silu -> XC (bf16); silu(z) -> ZS (bf16) ----------------
__global__ __launch_bounds__(256) void k_conv(const float* __restrict__ XZ,
    const float* __restrict__ cw, const float* __restrict__ cb,
    unsigned short* __restrict__ XC, unsigned short* __restrict__ ZS) {
  const int idx = blockIdx.x * 256 + threadIdx.x;  // over 2*NB*DI*L
  const int t = idx & (SEQL - 1);
  const int c = idx >> 11;
  const int d = c % DINNER;
  const int bb = c / DINNER;
  const int b = bb & (NBATCH - 1);
  const int dir = bb >> 1;
  const float* row = XZ + (size_t)(b*(2*DINNER) + d) * SEQL;
  float s = cb[d];
  const float w0 = cw[d*4+0], w1 = cw[d*4+1], w2 = cw[d*4+2], w3 = cw[d*4+3];
  if (dir == 0) {
    if (t >= 3) s += w0 * row[t-3];
    if (t >= 2) s += w1 * row[t-2];
    if (t >= 1) s += w2 * row[t-1];
    s += w3 * row[t];
  } else {
    int base = SEQL - 1 - t;
    if (base + 3 < SEQL) s += w0 * row[base+3];
    if (base + 2 < SEQL) s += w1 * row[base+2];
    if (base + 1 < SEQL) s += w2 * row[base+1];
    s += w3 * row[base];
  }
  XC[idx] = f2bf(silu_f(s));
  if (dir == 0) {
    float zv = XZ[(size_t)(b*(2*DINNER) + DINNER + d) * SEQL + t];
    ZS[(size_t)(b*DINNER + d) * SEQL + t] = f2bf(silu_f(zv));
  }
}

// ---------------- x_proj split-K partial: PART[ks][db][n][t] ----------------
__global__ __launch_bounds__(256) void k_xproj_part(const unsigned short* __restrict__ XC,
    const float* __restrict__ XPW, float* __restrict__ PART) {
  __shared__ float As[64][33];
  __shared__ float Ws[64][57];
  const int l0 = blockIdx.x * 32;
  const int ks = blockIdx.y;
  const int db = blockIdx.z;          // dir*NBATCH + b
  const int tid = threadIdx.x;
  const int ll = tid & 31, g = tid >> 5;  // 8 groups x 7 outputs
  const unsigned short* xc = XC + (size_t)db * DINNER * SEQL;
  float acc[7] = {};
  const int kbase = ks * KS;
  for (int k0 = kbase; k0 < kbase + KS; k0 += 64) {
#pragma unroll
    for (int i = 0; i < 8; ++i) {
      int e = tid + i*256;
      int kk = e >> 5, cc = e & 31;
      As[kk][cc] = bf2f(xc[(size_t)(k0 + kk) * SEQL + l0 + cc]);
    }
#pragma unroll
    for (int i = 0; i < 14; ++i) {
      int e = tid + i*256;
      if (e < 64*56) { int kk = e / 56, n = e % 56; Ws[kk][n] = XPW[(size_t)n * DINNER + k0 + kk]; }
    }
    __syncthreads();
#pragma unroll 8
    for (int kk = 0; kk < 64; ++kk) {
      float a = As[kk][ll];
#pragma unroll
      for (int i = 0; i < 7; ++i) acc[i] = fmaf(a, Ws[kk][g*7+i], acc[i]);
    }
    __syncthreads();
  }
#pragma unroll
  for (int i = 0; i < 7; ++i) {
    int n = g*7 + i;
    PART[((size_t)(ks*4 + db) * 56 + n) * SEQL + l0 + ll] = acc[i];
  }
}

// ---------------- x_proj reduce: sum partials -> DTR (fp32) / BC (bf16) ----------------
__global__ __launch_bounds__(256) void k_xred(const float* __restrict__ PART,
    float* __restrict__ DTR, unsigned short* __restrict__ BC) {
  const int idx = blockIdx.x * 256 + threadIdx.x;  // over 4*56*SEQL
  const int db = idx / (56 * SEQL);
  const int r  = idx % (56 * SEQL);
  const int n  = r / SEQL;
  const int t  = r % SEQL;
  float s = 0.f;
#pragma unroll
  for (int ks = 0; ks < KSPL; ++ks)
    s += PART[((size_t)(ks*4 + db) * 56 + n) * SEQL + t];
  if (n < DTRANK)
    DTR[((size_t)db * DTRANK + n) * SEQL + t] = s;
  else
    BC[((size_t)db * SEQL + t) * 32 + (n - DTRANK)] = f2bf(s);
}

// ---------------- dt_proj + softplus -> delta (bf16) ----------------
__global__ __launch_bounds__(256) void k_dtproj(const float* __restrict__ DTR,
    const float* __restrict__ WDT, const float* __restrict__ BDT,
    unsigned short* __restrict__ DELTA) {
  __shared__ float S[DTRANK][256];
  const int t0 = blockIdx.x * 256;
  const int d0 = blockIdx.y * 8;
  const int db = blockIdx.z;  // dir*NBATCH + b
  const int tid = threadIdx.x;
  const float* src = DTR + (size_t)(db * DTRANK) * SEQL;
#pragma unroll
  for (int r = 0; r < DTRANK; ++r) S[r][tid] = src[(size_t)r * SEQL + t0 + tid];
  __syncthreads();
#pragma unroll
  for (int i = 0; i < 8; ++i) {
    int d = d0 + i;
    float s = BDT[d];
#pragma unroll
    for (int r = 0; r < DTRANK; ++r) s = fmaf(WDT[d*DTRANK + r], S[r][tid], s);
    float sp = fmaxf(s, 0.f) + log1pf(__expf(-fabsf(s)));
    DELTA[(size_t)(db * DINNER + d) * SEQL + t0 + tid] = f2bf(sp);
  }
}

// ---------------- chunked scan pass 1: local scan (h0=0), 4 lanes x 4 states, bf16 in ----------------
__global__ __launch_bounds__(256) void k_scan1(const unsigned short* __restrict__ DELTA,
    const unsigned short* __restrict__ XC, const unsigned short* __restrict__ BC,
    const float* __restrict__ Alog, const float* __restrict__ Ablog,
    float* __restrict__ DS, float* __restrict__ HL) {
  const int tid = threadIdx.x;
  const int lk = tid & 3;                         // lane in quad = state quad
  const int gid = blockIdx.x * 64 + (tid >> 2);   // channel-chunk group
  const int c = gid & (NCHUNK - 1);
  const int ch = gid >> 5;                        // /NCHUNK (=32)
  const int d = ch % DINNER;
  const int rest = ch / DINNER;
  const int b = rest & (NBATCH - 1);
  const int dir = rest >> 1;
  const float* Ap = (dir ? Ablog : Alog) + (size_t)d * NSTATE + 4*lk;
  float Av[4];
#pragma unroll
  for (int j = 0; j < 4; ++j) Av[j] = -__expf(Ap[j]);
  const unsigned short* dlt_p = DELTA + (size_t)((dir*NBATCH + b) * DINNER + d) * SEQL;
  const unsigned short* xc_p  = XC   + (size_t)((dir*NBATCH + b) * DINNER + d) * SEQL;
  const unsigned short* bc_p  = BC   + (size_t)(dir*NBATCH + b) * SEQL * 32;
  float h[4] = {0.f, 0.f, 0.f, 0.f};
  float dsum = 0.f;
  const int t0 = c * CHUNK;
#pragma unroll 2
  for (int tb = t0; tb < t0 + CHUNK; tb += 4) {
    const int tl = tb + lk;
    float dltv = bf2f(dlt_p[tl]);
    float xvv  = bf2f(xc_p[tl]);
    float uv   = dltv * xvv;
    dsum += dltv;
#pragma unroll
    for (int k = 0; k < 4; ++k) {
      float dt_t = __shfl(dltv, k, 4);
      float u_t  = __shfl(uv, k, 4);
      ushort4 b4 = *(const ushort4*)&bc_p[(tb + k)*32 + 4*lk];
      float bb[4] = {bf2f(b4.x), bf2f(b4.y), bf2f(b4.z), bf2f(b4.w)};
#pragma unroll
      for (int j = 0; j < 4; ++j) {
        float dA = __expf(dt_t * Av[j]);
        h[j] = fmaf(dA, h[j], u_t * bb[j]);
      }
    }
  }
  dsum += __shfl_xor(dsum, 1, 4);
  dsum += __shfl_xor(dsum, 2, 4);
  if (lk == 0) DS[gid] = dsum;
  float4 hv = {h[0], h[1], h[2], h[3]};
  *(float4*)&HL[(size_t)gid * 16 + 4*lk] = hv;
}

// ---------------- fixup: h_start per chunk via P = exp(A * sum_delta) ----------------
__global__ __launch_bounds__(256) void k_scanfix(const float* __restrict__ DS,
    const float* __restrict__ HL, const float* __restrict__ Alog,
    const float* __restrict__ Ablog, float* __restrict__ HS) {
  const int idx = blockIdx.x * 256 + threadIdx.x;  // 0 .. NCH*16-1
  const int ch = idx >> 4;
  const int n = idx & 15;
  const int d = ch % DINNER;
  const int rest = ch / DINNER;
  const int dir = rest >> 1;
  const float Aval = -__expf((dir ? Ablog : Alog)[(size_t)d * NSTATE + n]);
  float h = 0.f;
#pragma unroll
  for (int c = 0; c < NCHUNK; ++c) {
    size_t off = ((size_t)ch * NCHUNK + c) * 16 + n;
    HS[off] = h;
    float p = __expf(DS[(size_t)ch * NCHUNK + c] * Aval);
    h = fmaf(p, h, HL[off]);
  }
}

// ---------------- chunked scan pass 2: recompute with true h_start, gated y (bf16 out) ----------------
__global__ __launch_bounds__(256) void k_scan2(const unsigned short* __restrict__ DELTA,
    const unsigned short* __restrict__ XC, const unsigned short* __restrict__ BC,
    const unsigned short* __restrict__ ZS, const float* __restrict__ Alog,
    const float* __restrict__ Ablog, const float* __restrict__ Dp,
    const float* __restrict__ HS, unsigned short* __restrict__ Y) {
  const int tid = threadIdx.x;
  const int lk = tid & 3;
  const int gid = blockIdx.x * 64 + (tid >> 2);
  const int c = gid & (NCHUNK - 1);
  const int ch = gid >> 5;
  const int d = ch % DINNER;
  const int rest = ch / DINNER;
  const int b = rest & (NBATCH - 1);
  const int dir = rest >> 1;
  const float* Ap = (dir ? Ablog : Alog) + (size_t)d * NSTATE + 4*lk;
  float Av[4];
#pragma unroll
  for (int j = 0; j < 4; ++j) Av[j] = -__expf(Ap[j]);
  const float Dd = Dp[d];
  const unsigned short* dlt_p = DELTA + (size_t)((dir*NBATCH + b) * DINNER + d) * SEQL;
  const unsigned short* xc_p  = XC   + (size_t)((dir*NBATCH + b) * DINNER + d) * SEQL;
  const unsigned short* bc_p  = BC   + (size_t)(dir*NBATCH + b) * SEQL * 32;
  const unsigned short* zs_p  = ZS   + (size_t)(b*DINNER + d) * SEQL;
  unsigned short* y_p = Y + (size_t)((dir*NBATCH + b) * DINNER + d) * SEQL;
  float4 h0 = *(const float4*)&HS[(size_t)gid * 16 + 4*lk];
  float h[4] = {h0.x, h0.y, h0.z, h0.w};
  const int t0 = c * CHUNK;
#pragma unroll 2
  for (int tb = t0; tb < t0 + CHUNK; tb += 4) {
    const int tl = tb + lk;
    float dltv = bf2f(dlt_p[tl]);
    float xvv  = bf2f(xc_p[tl]);
    float uv   = dltv * xvv;
    const int to_l = dir ? (SEQL - 1 - tl) : tl;
    float gz = bf2f(zs_p[to_l]);   // silu pre-applied
    float ysel = 0.f;
#pragma unroll
    for (int k = 0; k < 4; ++k) {
      float dt_t = __shfl(dltv, k, 4);
      float u_t  = __shfl(uv, k, 4);
      ushort4 b4 = *(const ushort4*)&bc_p[(tb + k)*32 + 4*lk];
      ushort4 c4 = *(const ushort4*)&bc_p[(tb + k)*32 + 16 + 4*lk];
      float bb[4] = {bf2f(b4.x), bf2f(b4.y), bf2f(b4.z), bf2f(b4.w)};
      float cc[4] = {bf2f(c4.x), bf2f(c4.y), bf2f(c4.z), bf2f(c4.w)};
      float py = 0.f;
#pragma unroll
      for (int j = 0; j < 4; ++j) {
        float dA = __expf(dt_t * Av[j]);
        h[j] = fmaf(dA, h[j], u_t * bb[j]);
        py = fmaf(h[j], cc[j], py);
      }
      py += __shfl_xor(py, 1, 4);
      py += __shfl_xor(py, 2, 4);
      if (lk == k) ysel = py;
    }
    float yv = fmaf(xvv, Dd, ysel) * gz;
    y_p[to_l] = f2bf(yv);
  }
}

// ---------------- out_proj (bf16 MFMA) + residual ----------------
// OUT[tok][o] = sum_k (y0[k][tok]+y1[k][tok]) * WO[o][k] + X[tok][o]
__global__ __launch_bounds__(256) void k_outproj(const unsigned short* __restrict__ Y,
    const float* __restrict__ WO, const float* __restrict__ X,
    float* __restrict__ OUT) {
  __shared__ unsigned short LA[64][40];   // [tok][k] (transposed stage)
  __shared__ unsigned short LB[64][40];   // [o][k]
  const int m0 = blockIdx.x * 64;         // token tile
  const int n0 = blockIdx.y * 64;         // output-dim tile
  const int tid = threadIdx.x, lane = tid & 63, w = tid >> 6;
  const int wm = (w >> 1) * 32, wn = (w & 1) * 32;
  const int fr = lane & 15, fg = lane >> 4;
  const int b = m0 >> 11, lb = m0 & (SEQL - 1);
  const unsigned short* y0 = Y + (size_t)b * DINNER * SEQL;
  const unsigned short* y1 = Y + (size_t)(NBATCH + b) * DINNER * SEQL;
  const int kk = tid >> 3, tg = (tid & 7) * 8;   // A staging: 32 k x 8 tok-groups
  const int srow = tid >> 2, skg = (tid & 3) * 8; // B staging
  f32x4 acc[2][2] = {};
  for (int k0 = 0; k0 < DINNER; k0 += 32) {
    const unsigned short* p0 = y0 + (size_t)(k0 + kk) * SEQL + lb + tg;
    const unsigned short* p1 = y1 + (size_t)(k0 + kk) * SEQL + lb + tg;
    u16x8 a0 = *(const u16x8*)p0;
    u16x8 a1 = *(const u16x8*)p1;
#pragma unroll
    for (int i = 0; i < 8; ++i) LA[tg + i][kk] = f2bf(bf2f(a0[i]) + bf2f(a1[i]));
    const float* gb = &WO[(size_t)(n0 + srow) * DINNER + k0 + skg];
    float4 b1 = *(const float4*)gb, b2 = *(const float4*)(gb + 4);
    u16x8 vb;
    vb[0]=f2bf(b1.x); vb[1]=f2bf(b1.y); vb[2]=f2bf(b1.z); vb[3]=f2bf(b1.w);
    vb[4]=f2bf(b2.x); vb[5]=f2bf(b2.y); vb[6]=f2bf(b2.z); vb[7]=f2bf(b2.w);
    *(u16x8*)&LB[srow][skg] = vb;
    __syncthreads();
    bf16x8 af[2], bfr[2];
    af[0]  = *(const bf16x8*)&LA[wm + fr][fg*8];
    af[1]  = *(const bf16x8*)&LA[wm + 16 + fr][fg*8];
    bfr[0] = *(const bf16x8*)&LB[wn + fr][fg*8];
    bfr[1] = *(const bf16x8*)&LB[wn + 16 + fr][fg*8];
#pragma unroll
    for (int i = 0; i < 2; ++i)
#pragma unroll
      for (int j = 0; j < 2; ++j)
        acc[i][j] = __builtin_amdgcn_mfma_f32_16x16x32_bf16(af[i], bfr[j], acc[i][j], 0, 0, 0);
    __syncthreads();
  }
#pragma unroll
  for (int i = 0; i < 2; ++i)
#pragma unroll
    for (int j = 0; j < 2; ++j)
#pragma unroll
      for (int r = 0; r < 4; ++r) {
        int tok = m0 + wm + i*16 + fg*4 + r;
        int o = n0 + wn + j*16 + fr;
        size_t off = (size_t)tok * DIMX + o;
        OUT[off] = acc[i][j][r] + X[off];
      }
}

extern "C" void kernel_launch(void* const* d_in, const int* in_sizes, int n_in,
                              void* d_out, int out_size, void* d_ws, size_t ws_size,
                              hipStream_t stream) {
  (void)in_sizes; (void)n_in; (void)out_size; (void)ws_size;
  const float* x         = (const float*)d_in[0];
  const float* lin_w     = (const float*)d_in[1];
  const float* lin_b     = (const float*)d_in[2];
  const float* ln_g      = (const float*)d_in[3];
  const float* ln_b      = (const float*)d_in[4];
  const float* in_proj_w = (const float*)d_in[5];
  const float* conv_w    = (const float*)d_in[6];
  const float* conv_b    = (const float*)d_in[7];
  const float* x_proj_w  = (const float*)d_in[8];
  const float* dt_proj_w = (const float*)d_in[9];
  const float* dt_proj_b = (const float*)d_in[10];
  const float* A_log     = (const float*)d_in[11];
  const float* A_b_log   = (const float*)d_in[12];
  const float* Dp        = (const float*)d_in[13];
  const float* out_proj_w= (const float*)d_in[14];
  float* out = (float*)d_out;

  float* ws = (float*)d_ws;
  float* h    = ws;  ws += (size_t)NTOK * DIMX;               // dead after k_inproj -> reused as HS
  float* xz   = ws;  ws += (size_t)NBATCH * 2*DINNER * SEQL;
  unsigned short* xc  = (unsigned short*)ws;  ws += (size_t)NCH * SEQL / 2;       // bf16 2*NB*DI*L
  unsigned short* dlt = (unsigned short*)ws;  ws += (size_t)NCH * SEQL / 2;       // bf16
  unsigned short* zs  = (unsigned short*)ws;  ws += (size_t)NBATCH * DINNER * SEQL / 2; // bf16
  float* dtr  = ws;  ws += (size_t)2 * NBATCH * DTRANK * SEQL;
  unsigned short* bc = (unsigned short*)ws;   ws += (size_t)2 * NBATCH * SEQL * 32 / 2; // bf16
  float* y01f = ws;  ws += (size_t)NCH * SEQL / 2;            // bf16 Y (+ PART overlay, fp32 1.84M < 3.1M)
  float* HLb  = ws;  ws += (size_t)NGRP * 16;
  float* DSb  = ws;  ws += (size_t)NGRP;
  unsigned short* y01 = (unsigned short*)y01f;
  float* HSb  = h;    // overlay: NGRP*16 == NTOK*DIMX, h dead after k_inproj
  float* PART = y01f; // overlay: KSPL*4*56*SEQL fp32 (1.84M) <= region (3.14M floats); PART dead after k_xred

  k_lin<<<dim3(NTOK/64, DIMX/64), 256, 0, stream>>>(x, lin_w, lin_b, h);
  k_ln<<<NTOK, 128, 0, stream>>>(h, ln_g, ln_b);
  k_inproj<<<dim3(NTOK/64, 2*DINNER/64), 256, 0, stream>>>(h, in_proj_w, xz);
  k_conv<<<(2*NBATCH*DINNER*SEQL)/256, 256, 0, stream>>>(xz, conv_w, conv_b, xc, zs);
  k_xproj_part<<<dim3(SEQL/32, KSPL, 2*NBATCH), 256, 0, stream>>>(xc, x_proj_w, PART);
  k_xred<<<(2*NBATCH*56*SEQL)/256, 256, 0, stream>>>(PART, dtr, bc);
  k_dtproj<<<dim3(SEQL/256, DINNER/8, 2*NBATCH), 256, 0, stream>>>(dtr, dt_proj_w, dt_proj_b, dlt);
  k_scan1<<<NGRP*4/256, 256, 0, stream>>>(dlt, xc, bc, A_log, A_b_log, DSb, HLb);
  k_scanfix<<<NCH*16/256, 256, 0, stream>>>(DSb, HLb, A_log, A_b_log, HSb);
  k_scan2<<<NGRP*4/256, 256, 0, stream>>>(dlt, xc, bc, zs, A_log, A_b_log, Dp, HSb, y01);
  k_outproj<<<dim3(NTOK/64, DIMX/64), 256, 0, stream>>>(y01, out_proj_w, x, out);
}

// Round 8
// 213.717 us; speedup vs baseline: 1.2516x; 1.1666x over previous
//
#include <hip/hip_runtime.h>
#include <math.h>

#define DIMX 384
#define SEQL 2048
#define NBATCH 2
#define DINNER 768
#define NSTATE 16
#define DTRANK 24
#define NTOK (NBATCH*SEQL)
#define NCHUNK 32
#define CHUNK (SEQL/NCHUNK)   // 64
#define NCH (2*NBATCH*DINNER) // 3072 channels (dir,b,d)
#define KSPL 4                // xproj K-split
#define KS (DINNER/KSPL)      // 192
#define CHSTR 72              // LDS row stride (ushorts) per chunk: 144B, 16B-aligned, 2-way bank alias only

typedef __attribute__((ext_vector_type(8))) short bf16x8;
typedef __attribute__((ext_vector_type(8))) unsigned short u16x8;
typedef __attribute__((ext_vector_type(4))) float f32x4;

__device__ __forceinline__ float silu_f(float x) {
  return x / (1.f + __expf(-x));
}

__device__ __forceinline__ unsigned short f2bf(float f) {
  unsigned int u = __float_as_uint(f);
  unsigned int r = u + 0x7fffu + ((u >> 16) & 1u);   // round-to-nearest-even
  return (unsigned short)(r >> 16);
}

__device__ __forceinline__ float bf2f(unsigned short u) {
  return __uint_as_float(((unsigned int)u) << 16);
}

// ---------------- GEMM1 (bf16 MFMA): H[m][j] = sum_k X[m][k]*W[j][k] + bias[j] ----------------
__global__ __launch_bounds__(256) void k_lin(const float* __restrict__ X,
    const float* __restrict__ W, const float* __restrict__ bias,
    float* __restrict__ H) {
  __shared__ unsigned short LA[64][40];
  __shared__ unsigned short LB[64][40];
  const int m0 = blockIdx.x * 64, n0 = blockIdx.y * 64;
  const int tid = threadIdx.x, lane = tid & 63, w = tid >> 6;
  const int wm = (w >> 1) * 32, wn = (w & 1) * 32;
  const int fr = lane & 15, fg = lane >> 4;
  const int srow = tid >> 2, skg = (tid & 3) * 8;
  f32x4 acc[2][2] = {};
  for (int k0 = 0; k0 < DIMX; k0 += 32) {
    const float* ga = &X[(size_t)(m0 + srow) * DIMX + k0 + skg];
    const float* gb = &W[(size_t)(n0 + srow) * DIMX + k0 + skg];
    float4 a1 = *(const float4*)ga, a2 = *(const float4*)(ga + 4);
    float4 b1 = *(const float4*)gb, b2 = *(const float4*)(gb + 4);
    u16x8 va, vb;
    va[0]=f2bf(a1.x); va[1]=f2bf(a1.y); va[2]=f2bf(a1.z); va[3]=f2bf(a1.w);
    va[4]=f2bf(a2.x); va[5]=f2bf(a2.y); va[6]=f2bf(a2.z); va[7]=f2bf(a2.w);
    vb[0]=f2bf(b1.x); vb[1]=f2bf(b1.y); vb[2]=f2bf(b1.z); vb[3]=f2bf(b1.w);
    vb[4]=f2bf(b2.x); vb[5]=f2bf(b2.y); vb[6]=f2bf(b2.z); vb[7]=f2bf(b2.w);
    *(u16x8*)&LA[srow][skg] = va;
    *(u16x8*)&LB[srow][skg] = vb;
    __syncthreads();
    bf16x8 af[2], bfr[2];
    af[0]  = *(const bf16x8*)&LA[wm + fr][fg*8];
    af[1]  = *(const bf16x8*)&LA[wm + 16 + fr][fg*8];
    bfr[0] = *(const bf16x8*)&LB[wn + fr][fg*8];
    bfr[1] = *(const bf16x8*)&LB[wn + 16 + fr][fg*8];
#pragma unroll
    for (int i = 0; i < 2; ++i)
#pragma unroll
      for (int j = 0; j < 2; ++j)
        acc[i][j] = __builtin_amdgcn_mfma_f32_16x16x32_bf16(af[i], bfr[j], acc[i][j], 0, 0, 0);
    __syncthreads();
  }
#pragma unroll
  for (int i = 0; i < 2; ++i)
#pragma unroll
    for (int j = 0; j < 2; ++j)
#pragma unroll
      for (int r = 0; r < 4; ++r) {
        int m = m0 + wm + i*16 + fg*4 + r;
        int n = n0 + wn + j*16 + fr;
        H[(size_t)m * DIMX + n] = acc[i][j][r] + bias[n];
      }
}

// ---------------- LayerNorm + ReLU (in place on H) ----------------
__global__ __launch_bounds__(128) void k_ln(float* __restrict__ H,
    const float* __restrict__ g, const float* __restrict__ bt) {
  const int tok = blockIdx.x;
  float* row = H + (size_t)tok * DIMX;
  const int tid = threadIdx.x;
  float v[3]; float s = 0.f, ss = 0.f;
#pragma unroll
  for (int i = 0; i < 3; ++i) { v[i] = row[tid + i*128]; s += v[i]; ss += v[i]*v[i]; }
  for (int o = 32; o; o >>= 1) { s += __shfl_down(s, o); ss += __shfl_down(ss, o); }
  __shared__ float red[4];
  if ((tid & 63) == 0) { red[(tid>>6)*2] = s; red[(tid>>6)*2+1] = ss; }
  __syncthreads();
  float S = red[0] + red[2], SS = red[1] + red[3];
  float mu = S / DIMX;
  float var = SS / DIMX - mu * mu;
  float inv = rsqrtf(var + 1e-5f);
#pragma unroll
  for (int i = 0; i < 3; ++i) {
    int j = tid + i*128;
    float t = (v[i] - mu) * inv * g[j] + bt[j];
    row[j] = t > 0.f ? t : 0.f;
  }
}

// ---------------- GEMM2 (bf16 MFMA): XZ[b][c][l] = sum_k H[b][l][k]*W2[c][k] ----------------
__global__ __launch_bounds__(256) void k_inproj(const float* __restrict__ H,
    const float* __restrict__ W2, float* __restrict__ XZ) {
  __shared__ unsigned short LA[64][40];   // [c][k]
  __shared__ unsigned short LB[64][40];   // [tok][k]
  const int n0 = blockIdx.x * 64;         // token tile
  const int m0 = blockIdx.y * 64;         // channel tile
  const int tid = threadIdx.x, lane = tid & 63, w = tid >> 6;
  const int wm = (w >> 1) * 32, wn = (w & 1) * 32;
  const int fr = lane & 15, fg = lane >> 4;
  const int srow = tid >> 2, skg = (tid & 3) * 8;
  f32x4 acc[2][2] = {};
  for (int k0 = 0; k0 < DIMX; k0 += 32) {
    const float* ga = &W2[(size_t)(m0 + srow) * DIMX + k0 + skg];
    const float* gb = &H[(size_t)(n0 + srow) * DIMX + k0 + skg];
    float4 a1 = *(const float4*)ga, a2 = *(const float4*)(ga + 4);
    float4 b1 = *(const float4*)gb, b2 = *(const float4*)(gb + 4);
    u16x8 va, vb;
    va[0]=f2bf(a1.x); va[1]=f2bf(a1.y); va[2]=f2bf(a1.z); va[3]=f2bf(a1.w);
    va[4]=f2bf(a2.x); va[5]=f2bf(a2.y); va[6]=f2bf(a2.z); va[7]=f2bf(a2.w);
    vb[0]=f2bf(b1.x); vb[1]=f2bf(b1.y); vb[2]=f2bf(b1.z); vb[3]=f2bf(b1.w);
    vb[4]=f2bf(b2.x); vb[5]=f2bf(b2.y); vb[6]=f2bf(b2.z); vb[7]=f2bf(b2.w);
    *(u16x8*)&LA[srow][skg] = va;
    *(u16x8*)&LB[srow][skg] = vb;
    __syncthreads();
    bf16x8 af[2], bfr[2];
    af[0]  = *(const bf16x8*)&LA[wm + fr][fg*8];
    af[1]  = *(const bf16x8*)&LA[wm + 16 + fr][fg*8];
    bfr[0] = *(const bf16x8*)&LB[wn + fr][fg*8];
    bfr[1] = *(const bf16x8*)&LB[wn + 16 + fr][fg*8];
#pragma unroll
    for (int i = 0; i < 2; ++i)
#pragma unroll
      for (int j = 0; j < 2; ++j)
        acc[i][j] = __builtin_amdgcn_mfma_f32_16x16x32_bf16(af[i], bfr[j], acc[i][j], 0, 0, 0);
    __syncthreads();
  }
  const int b = n0 >> 11;
  const int lbase = n0 & (SEQL - 1);
#pragma unroll
  for (int i = 0; i < 2; ++i)
#pragma unroll
    for (int j = 0; j < 2; ++j)
#pragma unroll
      for (int r = 0; r < 4; ++r) {
        int c = m0 + wm + i*16 + fg*4 + r;
        int l = lbase + wn + j*16 + fr;
        XZ[((size_t)(b*(2*DINNER) + c)) * SEQL + l] = acc[i][j][r];
      }
}

// ---------------- causal depthwise conv + silu -> XC (bf16); silu(z) -> ZS (bf16) ----------------
__global__ __launch_bounds__(256) void k_conv(const float* __restrict__ XZ,
    const float* __restrict__ cw, const float* __restrict__ cb,
    unsigned short* __restrict__ XC, unsigned short* __restrict__ ZS) {
  const int idx = blockIdx.x * 256 + threadIdx.x;  // over 2*NB*DI*L
  const int t = idx & (SEQL - 1);
  const int c = idx >> 11;
  const int d = c % DINNER;
  const int bb = c / DINNER;
  const int b = bb & (NBATCH - 1);
  const int dir = bb >> 1;
  const float* row = XZ + (size_t)(b*(2*DINNER) + d) * SEQL;
  float s = cb[d];
  const float w0 = cw[d*4+0], w1 = cw[d*4+1], w2 = cw[d*4+2], w3 = cw[d*4+3];
  if (dir == 0) {
    if (t >= 3) s += w0 * row[t-3];
    if (t >= 2) s += w1 * row[t-2];
    if (t >= 1) s += w2 * row[t-1];
    s += w3 * row[t];
  } else {
    int base = SEQL - 1 - t;
    if (base + 3 < SEQL) s += w0 * row[base+3];
    if (base + 2 < SEQL) s += w1 * row[base+2];
    if (base + 1 < SEQL) s += w2 * row[base+1];
    s += w3 * row[base];
  }
  XC[idx] = f2bf(silu_f(s));
  if (dir == 0) {
    float zv = XZ[(size_t)(b*(2*DINNER) + DINNER + d) * SEQL + t];
    ZS[(size_t)(b*DINNER + d) * SEQL + t] = f2bf(silu_f(zv));
  }
}

// ---------------- x_proj split-K partial: PART[ks][db][n][t] ----------------
__global__ __launch_bounds__(256) void k_xproj_part(const unsigned short* __restrict__ XC,
    const float* __restrict__ XPW, float* __restrict__ PART) {
  __shared__ float As[64][33];
  __shared__ float Ws[64][57];
  const int l0 = blockIdx.x * 32;
  const int ks = blockIdx.y;
  const int db = blockIdx.z;          // dir*NBATCH + b
  const int tid = threadIdx.x;
  const int ll = tid & 31, g = tid >> 5;  // 8 groups x 7 outputs
  const unsigned short* xc = XC + (size_t)db * DINNER * SEQL;
  float acc[7] = {};
  const int kbase = ks * KS;
  for (int k0 = kbase; k0 < kbase + KS; k0 += 64) {
#pragma unroll
    for (int i = 0; i < 8; ++i) {
      int e = tid + i*256;
      int kk = e >> 5, cc = e & 31;
      As[kk][cc] = bf2f(xc[(size_t)(k0 + kk) * SEQL + l0 + cc]);
    }
#pragma unroll
    for (int i = 0; i < 14; ++i) {
      int e = tid + i*256;
      if (e < 64*56) { int kk = e / 56, n = e % 56; Ws[kk][n] = XPW[(size_t)n * DINNER + k0 + kk]; }
    }
    __syncthreads();
#pragma unroll 8
    for (int kk = 0; kk < 64; ++kk) {
      float a = As[kk][ll];
#pragma unroll
      for (int i = 0; i < 7; ++i) acc[i] = fmaf(a, Ws[kk][g*7+i], acc[i]);
    }
    __syncthreads();
  }
#pragma unroll
  for (int i = 0; i < 7; ++i) {
    int n = g*7 + i;
    PART[((size_t)(ks*4 + db) * 56 + n) * SEQL + l0 + ll] = acc[i];
  }
}

// ---------------- x_proj reduce: sum partials -> DTR (fp32) / BC (bf16) ----------------
__global__ __launch_bounds__(256) void k_xred(const float* __restrict__ PART,
    float* __restrict__ DTR, unsigned short* __restrict__ BC) {
  const int idx = blockIdx.x * 256 + threadIdx.x;  // over 4*56*SEQL
  const int db = idx / (56 * SEQL);
  const int r  = idx % (56 * SEQL);
  const int n  = r / SEQL;
  const int t  = r % SEQL;
  float s = 0.f;
#pragma unroll
  for (int ks = 0; ks < KSPL; ++ks)
    s += PART[((size_t)(ks*4 + db) * 56 + n) * SEQL + t];
  if (n < DTRANK)
    DTR[((size_t)db * DTRANK + n) * SEQL + t] = s;
  else
    BC[((size_t)db * SEQL + t) * 32 + (n - DTRANK)] = f2bf(s);
}

// ---------------- dt_proj + softplus -> delta (bf16) ----------------
__global__ __launch_bounds__(256) void k_dtproj(const float* __restrict__ DTR,
    const float* __restrict__ WDT, const float* __restrict__ BDT,
    unsigned short* __restrict__ DELTA) {
  __shared__ float S[DTRANK][256];
  const int t0 = blockIdx.x * 256;
  const int d0 = blockIdx.y * 8;
  const int db = blockIdx.z;  // dir*NBATCH + b
  const int tid = threadIdx.x;
  const float* src = DTR + (size_t)(db * DTRANK) * SEQL;
#pragma unroll
  for (int r = 0; r < DTRANK; ++r) S[r][tid] = src[(size_t)r * SEQL + t0 + tid];
  __syncthreads();
#pragma unroll
  for (int i = 0; i < 8; ++i) {
    int d = d0 + i;
    float s = BDT[d];
#pragma unroll
    for (int r = 0; r < DTRANK; ++r) s = fmaf(WDT[d*DTRANK + r], S[r][tid], s);
    float sp = fmaxf(s, 0.f) + log1pf(__expf(-fabsf(s)));
    DELTA[(size_t)(db * DINNER + d) * SEQL + t0 + tid] = f2bf(sp);
  }
}

// ---------------- fused selective scan: one block = one channel (all 32 chunks) ----------------
// 128 threads = 32 quads; quad cq handles chunk cq (64 steps). Lane lk owns states 4lk..4lk+3.
// Pass1 (h0=0, record sum-delta + local h_end) -> in-LDS fixup -> pass2 (true h_start, gated y).
__global__ __launch_bounds__(128) void k_scanf(const unsigned short* __restrict__ DELTA,
    const unsigned short* __restrict__ XC, const unsigned short* __restrict__ BC,
    const unsigned short* __restrict__ ZS, const float* __restrict__ Alog,
    const float* __restrict__ Ablog, const float* __restrict__ Dp,
    unsigned short* __restrict__ Y) {
  __shared__ __align__(16) unsigned short sd[NCHUNK * CHSTR];  // delta (bf16)
  __shared__ __align__(16) unsigned short sx[NCHUNK * CHSTR];  // conv+silu x (bf16)
  __shared__ __align__(16) unsigned short sz[NCHUNK * CHSTR];  // silu(z), natural order (bf16)
  __shared__ __align__(16) unsigned short sy[NCHUNK * CHSTR];  // y staging, natural order (bf16)
  __shared__ float sHL[NCHUNK][16];
  __shared__ float sHS[NCHUNK][16];
  __shared__ float sDS[NCHUNK];
  const int tid = threadIdx.x;
  const int ch = blockIdx.x;          // 0..NCH-1
  const int db = ch / DINNER;         // dir*2 + b
  const int d  = ch % DINNER;
  const int b  = db & 1, dir = db >> 1;
  const unsigned short* gd = DELTA + (size_t)(db * DINNER + d) * SEQL;
  const unsigned short* gx = XC    + (size_t)(db * DINNER + d) * SEQL;
  const unsigned short* gz = ZS    + (size_t)(b * DINNER + d) * SEQL;
  const unsigned short* bc_p = BC  + (size_t)db * SEQL * 32;
  // ---- stage streams into LDS (coalesced ushort8) ----
#pragma unroll
  for (int i = 0; i < 2; ++i) {
    int e = (i * 128 + tid) * 8;
    int r = e >> 6, cl = e & 63;
    *(u16x8*)&sd[r * CHSTR + cl] = *(const u16x8*)&gd[e];
    *(u16x8*)&sx[r * CHSTR + cl] = *(const u16x8*)&gx[e];
    *(u16x8*)&sz[r * CHSTR + cl] = *(const u16x8*)&gz[e];
  }
  const int lk = tid & 3;            // state-quad lane
  const int cq = tid >> 2;           // chunk 0..31
  const int t0 = cq * CHUNK;
  const float* Ap = (dir ? Ablog : Alog) + (size_t)d * NSTATE + 4 * lk;
  float Av[4];
#pragma unroll
  for (int j = 0; j < 4; ++j) Av[j] = -__expf(Ap[j]);
  __syncthreads();
  // ---- pass 1: local scan, h0 = 0 ----
  {
    float h0_ = 0.f, h1_ = 0.f, h2_ = 0.f, h3_ = 0.f;
    float dsum = 0.f;
#pragma unroll 2
    for (int tb4 = 0; tb4 < CHUNK; tb4 += 4) {
      const int base = cq * CHSTR + tb4;
      ushort4 dl4 = *(const ushort4*)&sd[base];   // quad-broadcast 8B
      ushort4 xl4 = *(const ushort4*)&sx[base];
      float dl[4] = {bf2f(dl4.x), bf2f(dl4.y), bf2f(dl4.z), bf2f(dl4.w)};
      float xl[4] = {bf2f(xl4.x), bf2f(xl4.y), bf2f(xl4.z), bf2f(xl4.w)};
      dsum += dl[0] + dl[1] + dl[2] + dl[3];
#pragma unroll
      for (int k = 0; k < 4; ++k) {
        float u = dl[k] * xl[k];
        ushort4 b4 = *(const ushort4*)&bc_p[(size_t)(t0 + tb4 + k) * 32 + 4 * lk];
        float dA0 = __expf(dl[k] * Av[0]);
        float dA1 = __expf(dl[k] * Av[1]);
        float dA2 = __expf(dl[k] * Av[2]);
        float dA3 = __expf(dl[k] * Av[3]);
        h0_ = fmaf(dA0, h0_, u * bf2f(b4.x));
        h1_ = fmaf(dA1, h1_, u * bf2f(b4.y));
        h2_ = fmaf(dA2, h2_, u * bf2f(b4.z));
        h3_ = fmaf(dA3, h3_, u * bf2f(b4.w));
      }
    }
    if (lk == 0) sDS[cq] = dsum;
    float4 hv = {h0_, h1_, h2_, h3_};
    *(float4*)&sHL[cq][4 * lk] = hv;
  }
  __syncthreads();
  // ---- fixup: serial chain over 32 chunk summaries, one thread per state ----
  if (tid < NSTATE) {
    const int n = tid;
    const float Aval = -__expf((dir ? Ablog : Alog)[(size_t)d * NSTATE + n]);
    float hh = 0.f;
#pragma unroll
    for (int c2 = 0; c2 < NCHUNK; ++c2) {
      sHS[c2][n] = hh;
      hh = fmaf(__expf(sDS[c2] * Aval), hh, sHL[c2][n]);
    }
  }
  __syncthreads();
  // ---- pass 2: recompute with true h_start, emit gated y into sy ----
  {
    const float Dd = Dp[d];
    float4 h0v = *(const float4*)&sHS[cq][4 * lk];
    float h0_ = h0v.x, h1_ = h0v.y, h2_ = h0v.z, h3_ = h0v.w;
#pragma unroll 2
    for (int tb4 = 0; tb4 < CHUNK; tb4 += 4) {
      const int base = cq * CHSTR + tb4;
      ushort4 dl4 = *(const ushort4*)&sd[base];
      ushort4 xl4 = *(const ushort4*)&sx[base];
      float dl[4] = {bf2f(dl4.x), bf2f(dl4.y), bf2f(dl4.z), bf2f(dl4.w)};
      float xl[4] = {bf2f(xl4.x), bf2f(xl4.y), bf2f(xl4.z), bf2f(xl4.w)};
      float pp[4];
#pragma unroll
      for (int k = 0; k < 4; ++k) {
        float u = dl[k] * xl[k];
        ushort4 b4 = *(const ushort4*)&bc_p[(size_t)(t0 + tb4 + k) * 32 + 4 * lk];
        ushort4 c4 = *(const ushort4*)&bc_p[(size_t)(t0 + tb4 + k) * 32 + 16 + 4 * lk];
        float dA0 = __expf(dl[k] * Av[0]);
        float dA1 = __expf(dl[k] * Av[1]);
        float dA2 = __expf(dl[k] * Av[2]);
        float dA3 = __expf(dl[k] * Av[3]);
        h0_ = fmaf(dA0, h0_, u * bf2f(b4.x));
        h1_ = fmaf(dA1, h1_, u * bf2f(b4.y));
        h2_ = fmaf(dA2, h2_, u * bf2f(b4.z));
        h3_ = fmaf(dA3, h3_, u * bf2f(b4.w));
        float py = h0_ * bf2f(c4.x);
        py = fmaf(h1_, bf2f(c4.y), py);
        py = fmaf(h2_, bf2f(c4.z), py);
        py = fmaf(h3_, bf2f(c4.w), py);
        pp[k] = py;
      }
      // 4x4 quad transpose-reduce: lane lk ends with sum over lanes of pp[lk]
      const int i0 = lk & 1;
      float u0 = __shfl_xor(pp[i0 ^ 1], 1, 4);
      float u1 = __shfl_xor(pp[(i0 ^ 1) + 2], 1, 4);
      float s0 = pp[i0] + u0;
      float s1 = pp[i0 + 2] + u1;
      float send = (lk & 2) ? s0 : s1;
      float v = __shfl_xor(send, 2, 4);
      float keep = (lk & 2) ? s1 : s0;
      float ysum = keep + v;
      const int tl = t0 + tb4 + lk;
      const int to_l = dir ? (SEQL - 1 - tl) : tl;
      float gzv = bf2f(sz[(to_l >> 6) * CHSTR + (to_l & 63)]);
      float yv = fmaf(xl[lk], Dd, ysum) * gzv;
      sy[(to_l >> 6) * CHSTR + (to_l & 63)] = f2bf(yv);
    }
  }
  __syncthreads();
  // ---- write y out coalesced ----
  unsigned short* gy = Y + (size_t)(db * DINNER + d) * SEQL;
#pragma unroll
  for (int i = 0; i < 2; ++i) {
    int e = (i * 128 + tid) * 8;
    int r = e >> 6, cl = e & 63;
    *(u16x8*)&gy[e] = *(const u16x8*)&sy[r * CHSTR + cl];
  }
}

// ---------------- out_proj (bf16 MFMA) + residual ----------------
// OUT[tok][o] = sum_k (y0[k][tok]+y1[k][tok]) * WO[o][k] + X[tok][o]
__global__ __launch_bounds__(256) void k_outproj(const unsigned short* __restrict__ Y,
    const float* __restrict__ WO, const float* __restrict__ X,
    float* __restrict__ OUT) {
  __shared__ unsigned short LA[64][40];   // [tok][k] (transposed stage)
  __shared__ unsigned short LB[64][40];   // [o][k]
  const int m0 = blockIdx.x * 64;         // token tile
  const int n0 = blockIdx.y * 64;         // output-dim tile
  const int tid = threadIdx.x, lane = tid & 63, w = tid >> 6;
  const int wm = (w >> 1) * 32, wn = (w & 1) * 32;
  const int fr = lane & 15, fg = lane >> 4;
  const int b = m0 >> 11, lb = m0 & (SEQL - 1);
  const unsigned short* y0 = Y + (size_t)b * DINNER * SEQL;
  const unsigned short* y1 = Y + (size_t)(NBATCH + b) * DINNER * SEQL;
  const int kk = tid >> 3, tg = (tid & 7) * 8;   // A staging: 32 k x 8 tok-groups
  const int srow = tid >> 2, skg = (tid & 3) * 8; // B staging
  f32x4 acc[2][2] = {};
  for (int k0 = 0; k0 < DINNER; k0 += 32) {
    const unsigned short* p0 = y0 + (size_t)(k0 + kk) * SEQL + lb + tg;
    const unsigned short* p1 = y1 + (size_t)(k0 + kk) * SEQL + lb + tg;
    u16x8 a0 = *(const u16x8*)p0;
    u16x8 a1 = *(const u16x8*)p1;
#pragma unroll
    for (int i = 0; i < 8; ++i) LA[tg + i][kk] = f2bf(bf2f(a0[i]) + bf2f(a1[i]));
    const float* gb = &WO[(size_t)(n0 + srow) * DINNER + k0 + skg];
    float4 b1 = *(const float4*)gb, b2 = *(const float4*)(gb + 4);
    u16x8 vb;
    vb[0]=f2bf(b1.x); vb[1]=f2bf(b1.y); vb[2]=f2bf(b1.z); vb[3]=f2bf(b1.w);
    vb[4]=f2bf(b2.x); vb[5]=f2bf(b2.y); vb[6]=f2bf(b2.z); vb[7]=f2bf(b2.w);
    *(u16x8*)&LB[srow][skg] = vb;
    __syncthreads();
    bf16x8 af[2], bfr[2];
    af[0]  = *(const bf16x8*)&LA[wm + fr][fg*8];
    af[1]  = *(const bf16x8*)&LA[wm + 16 + fr][fg*8];
    bfr[0] = *(const bf16x8*)&LB[wn + fr][fg*8];
    bfr[1] = *(const bf16x8*)&LB[wn + 16 + fr][fg*8];
#pragma unroll
    for (int i = 0; i < 2; ++i)
#pragma unroll
      for (int j = 0; j < 2; ++j)
        acc[i][j] = __builtin_amdgcn_mfma_f32_16x16x32_bf16(af[i], bfr[j], acc[i][j], 0, 0, 0);
    __syncthreads();
  }
#pragma unroll
  for (int i = 0; i < 2; ++i)
#pragma unroll
    for (int j = 0; j < 2; ++j)
#pragma unroll
      for (int r = 0; r < 4; ++r) {
        int tok = m0 + wm + i*16 + fg*4 + r;
        int o = n0 + wn + j*16 + fr;
        size_t off = (size_t)tok * DIMX + o;
        OUT[off] = acc[i][j][r] + X[off];
      }
}

extern "C" void kernel_launch(void* const* d_in, const int* in_sizes, int n_in,
                              void* d_out, int out_size, void* d_ws, size_t ws_size,
                              hipStream_t stream) {
  (void)in_sizes; (void)n_in; (void)out_size; (void)ws_size;
  const float* x         = (const float*)d_in[0];
  const float* lin_w     = (const float*)d_in[1];
  const float* lin_b     = (const float*)d_in[2];
  const float* ln_g      = (const float*)d_in[3];
  const float* ln_b      = (const float*)d_in[4];
  const float* in_proj_w = (const float*)d_in[5];
  const float* conv_w    = (const float*)d_in[6];
  const float* conv_b    = (const float*)d_in[7];
  const float* x_proj_w  = (const float*)d_in[8];
  const float* dt_proj_w = (const float*)d_in[9];
  const float* dt_proj_b = (const float*)d_in[10];
  const float* A_log     = (const float*)d_in[11];
  const float* A_b_log   = (const float*)d_in[12];
  const float* Dp        = (const float*)d_in[13];
  const float* out_proj_w= (const float*)d_in[14];
  float* out = (float*)d_out;

  float* ws = (float*)d_ws;
  float* h    = ws;  ws += (size_t)NTOK * DIMX;               // dead after k_inproj
  float* xz   = ws;  ws += (size_t)NBATCH * 2*DINNER * SEQL;
  unsigned short* xc  = (unsigned short*)ws;  ws += (size_t)NCH * SEQL / 2;       // bf16
  unsigned short* dlt = (unsigned short*)ws;  ws += (size_t)NCH * SEQL / 2;       // bf16
  unsigned short* zs  = (unsigned short*)ws;  ws += (size_t)NBATCH * DINNER * SEQL / 2; // bf16
  float* dtr  = ws;  ws += (size_t)2 * NBATCH * DTRANK * SEQL;
  unsigned short* bc = (unsigned short*)ws;   ws += (size_t)2 * NBATCH * SEQL * 32 / 2; // bf16
  float* y01f = ws;  ws += (size_t)NCH * SEQL / 2;            // bf16 Y (+ PART overlay)
  unsigned short* y01 = (unsigned short*)y01f;
  float* PART = y01f; // overlay: KSPL*4*56*SEQL fp32 (1.84M) <= region (3.14M floats); PART dead after k_xred

  k_lin<<<dim3(NTOK/64, DIMX/64), 256, 0, stream>>>(x, lin_w, lin_b, h);
  k_ln<<<NTOK, 128, 0, stream>>>(h, ln_g, ln_b);
  k_inproj<<<dim3(NTOK/64, 2*DINNER/64), 256, 0, stream>>>(h, in_proj_w, xz);
  k_conv<<<(2*NBATCH*DINNER*SEQL)/256, 256, 0, stream>>>(xz, conv_w, conv_b, xc, zs);
  k_xproj_part<<<dim3(SEQL/32, KSPL, 2*NBATCH), 256, 0, stream>>>(xc, x_proj_w, PART);
  k_xred<<<(2*NBATCH*56*SEQL)/256, 256, 0, stream>>>(PART, dtr, bc);
  k_dtproj<<<dim3(SEQL/256, DINNER/8, 2*NBATCH), 256, 0, stream>>>(dtr, dt_proj_w, dt_proj_b, dlt);
  k_scanf<<<NCH, 128, 0, stream>>>(dlt, xc, bc, zs, A_log, A_b_log, Dp, y01);
  k_outproj<<<dim3(NTOK/64, DIMX/64), 256, 0, stream>>>(y01, out_proj_w, x, out);
}